// Round 9
// baseline (880.205 us; speedup 1.0000x reference)
//
#include <hip/hip_runtime.h>

#define D 64
#define N_GRAPHS 128
#define D_OUT 16
#define BCAP 16384   // max edges per 256-node bucket (avg 6400, sigma ~80)
#define TILE 4096    // edges per bin_kernel block
#define ECAP 2048    // max edges per 32-node block staged in LDS (avg 800)

typedef unsigned short u16;
typedef unsigned int u32;
typedef unsigned char u8;
typedef __attribute__((ext_vector_type(8))) short bf16x8;
typedef __attribute__((ext_vector_type(4))) float f32x4;
typedef __attribute__((ext_vector_type(2))) float f32x2;

__device__ inline u16 f2bf(float f) {  // round-to-nearest-even
  u32 u = __float_as_uint(f);
  return (u16)((u + 0x7fffu + ((u >> 16) & 1u)) >> 16);
}
__device__ inline float bf2f(u16 b) { return __uint_as_float((u32)b << 16); }
__device__ inline f32x2 bfpair(u32 v) {
  return (f32x2){__uint_as_float(v << 16), __uint_as_float(v & 0xffff0000u)};
}

// ===========================================================================
// Merged front-end: blocks [0,nbin) = edge binning; blocks [nbin,...) =
// x->bf16 convert + weight precompute (overlap on CU array). cursors pre-zeroed.
// ===========================================================================
__global__ __launch_bounds__(256) void cvtbin_kernel(
    const float* __restrict__ xin, u16* __restrict__ hX, int n4, int nbin,
    const int* __restrict__ src, const int* __restrict__ dst,
    int* __restrict__ cursors, u32* __restrict__ binned, int n_edges, int nbuck,
    const float* __restrict__ Wrel1, const float* __restrict__ Wroot1,
    const float* __restrict__ Wrel2, const float* __restrict__ Wroot2,
    const float* __restrict__ Wrel3, const float* __restrict__ Wroot3,
    const float* __restrict__ Wlin, const float* __restrict__ brel3,
    const float* __restrict__ blin,
    float* __restrict__ M1, float* __restrict__ M2, float* __restrict__ cvec,
    u16* __restrict__ WbT1r, u16* __restrict__ WbT1o,
    u16* __restrict__ WbT2r, u16* __restrict__ WbT2o) {
  __shared__ u32 ent[TILE];
  __shared__ u8 ebk[TILE];
  __shared__ int hist[256];
  __shared__ int startb[256];
  __shared__ int cur[256];
  __shared__ int gbase[256];
  int t = threadIdx.x;

  if ((int)blockIdx.x < nbin) {
    hist[t] = 0;
    __syncthreads();
    int base = blockIdx.x * TILE;
    int cnt = n_edges - base;
    if (cnt > TILE) cnt = TILE;

    int mys[16], myd[16];
#pragma unroll
    for (int j = 0; j < 16; j++) {
      int i = base + t + j * 256;
      if (t + j * 256 < cnt) {
        mys[j] = src[i];
        myd[j] = dst[i];
        atomicAdd(&hist[myd[j] >> 8], 1);
      } else {
        myd[j] = -1;
      }
    }
    __syncthreads();
    int myc = hist[t];
    for (int off = 1; off < 256; off <<= 1) {
      int tmp = (t >= off) ? hist[t - off] : 0;
      __syncthreads();
      hist[t] += tmp;
      __syncthreads();
    }
    int excl = hist[t] - myc;
    startb[t] = excl;
    cur[t] = excl;
    __syncthreads();

#pragma unroll
    for (int j = 0; j < 16; j++) {
      if (myd[j] >= 0) {
        int b = myd[j] >> 8;
        int p = atomicAdd(&cur[b], 1);
        ent[p] = ((u32)myd[j] << 16) | (u32)mys[j];
        ebk[p] = (u8)b;
      }
    }
    __syncthreads();

    if (t < nbuck && myc > 0) gbase[t] = atomicAdd(&cursors[t], myc);
    __syncthreads();

#pragma unroll
    for (int j = 0; j < 16; j++) {
      int p = t + j * 256;
      if (p < cnt) {
        int b = ebk[p];
        int gpos = gbase[b] + (p - startb[b]);
        if (gpos < BCAP) binned[(size_t)b * BCAP + gpos] = ent[p];
      }
    }
    return;
  }

  int cb = blockIdx.x - nbin;
  if (cb == 0) {
    if (t >= 240) {
      int o = t - 240;
      float c = blin[o];
#pragma unroll
      for (int j = 0; j < D; j++) c = fmaf(brel3[j], Wlin[j * D_OUT + o], c);
      cvec[o] = c;
    }
  } else if (cb <= 8) {
    int idx = (cb - 1) * 256 + t;
    const float* W = (idx < 1024) ? Wrel3 : Wroot3;
    float* M = (idx < 1024) ? M1 : M2;
    int id = idx & 1023;
    int k = id >> 4, o = id & 15;
    float acc = 0.0f;
#pragma unroll
    for (int j = 0; j < D; j++) acc = fmaf(W[k * D + j], Wlin[j * D_OUT + o], acc);
    M[id] = acc;
  } else if (cb <= 16) {
    int tid = (cb - 9) * 256 + t;
    int mat = tid >> 9;
    int r = tid & 511;
    int o = r >> 3;
    int k0 = (r & 7) * 8;
    const float* Wsrc = (mat == 0) ? Wrel1 : (mat == 1) ? Wroot1
                       : (mat == 2) ? Wrel2 : Wroot2;
    u16* Wdst = (mat == 0) ? WbT1r : (mat == 1) ? WbT1o
               : (mat == 2) ? WbT2r : WbT2o;
    u16 tmp[8];
#pragma unroll
    for (int j = 0; j < 8; j++) tmp[j] = f2bf(Wsrc[(k0 + j) * D + o]);
    uint4 pw;
    pw.x = (u32)tmp[0] | ((u32)tmp[1] << 16);
    pw.y = (u32)tmp[2] | ((u32)tmp[3] << 16);
    pw.z = (u32)tmp[4] | ((u32)tmp[5] << 16);
    pw.w = (u32)tmp[6] | ((u32)tmp[7] << 16);
    *(uint4*)&Wdst[o * D + k0] = pw;
  }
  int i = cb * 256 + t;
  if (i >= n4) return;
  float4 v = ((const float4*)xin)[i];
  ushort4 o4;
  o4.x = f2bf(v.x); o4.y = f2bf(v.y); o4.z = f2bf(v.z); o4.w = f2bf(v.w);
  ((ushort4*)hX)[i] = o4;
}

// ===========================================================================
// CSR pass 2: one block per bucket; own edge-base prefix; LDS CSR build.
// ===========================================================================
__global__ __launch_bounds__(256) void csr_kernel(
    const u32* __restrict__ binned, const int* __restrict__ cursors,
    u16* __restrict__ csr_src, int* __restrict__ offsets,
    int n_nodes, int nbuck) {
  __shared__ int deg[256];
  __shared__ int cur[256];
  __shared__ int red[256];
  __shared__ u16 lcsr[BCAP];
  int b = blockIdx.x, t = threadIdx.x;
  int cnt = cursors[b];
  if (cnt < 0) cnt = 0;
  if (cnt > BCAP) cnt = BCAP;

  int c = 0;
  if (t < b) {
    c = cursors[t];
    if (c < 0) c = 0;
    if (c > BCAP) c = BCAP;
  }
  red[t] = c;
  __syncthreads();
  for (int off = 128; off > 0; off >>= 1) {
    if (t < off) red[t] += red[t + off];
    __syncthreads();
  }
  int ebase = red[0];

  int nodeBase = b << 8;
  int nn = n_nodes - nodeBase;
  if (nn > 256) nn = 256;

  deg[t] = 0;
  __syncthreads();
  const u32* be = binned + (size_t)b * BCAP;
  for (int i = t; i < cnt; i += 256)
    atomicAdd(&deg[(be[i] >> 16) - nodeBase], 1);
  __syncthreads();
  int myd = deg[t];
  for (int off = 1; off < 256; off <<= 1) {
    int tmp = (t >= off) ? deg[t - off] : 0;
    __syncthreads();
    deg[t] += tmp;
    __syncthreads();
  }
  int loff = deg[t] - myd;
  cur[t] = loff;
  if (t < nn) offsets[nodeBase + t] = ebase + loff;
  if (b == nbuck - 1 && t == 0) offsets[n_nodes] = ebase + cnt;
  __syncthreads();

  for (int i = t; i < cnt; i += 256) {
    u32 e = be[i];
    int ln = (e >> 16) - nodeBase;
    int p = atomicAdd(&cur[ln], 1);
    lcsr[p] = (u16)(e & 0xffffu);
  }
  __syncthreads();
  for (int i = t; i < cnt; i += 256) csr_src[ebase + i] = lcsr[i];
}

// Prologue: soff -> LDS, degree-rank perm, contiguous csr run staged to LDS.
#define GATHER_PROLOGUE(soff, permAr, eidx, blockBase, n_nodes, offsets, csr_src, gsrc, ebase0, scnt) \
  {                                                                     \
    int t_ = threadIdx.x;                                               \
    if (t_ < 33) {                                                      \
      int idx = blockBase + t_;                                         \
      if (idx > n_nodes) idx = n_nodes;                                 \
      soff[t_] = offsets[idx];                                          \
    }                                                                   \
    __syncthreads();                                                    \
    ebase0 = soff[0];                                                   \
    int ecnt_ = soff[32] - ebase0;                                      \
    scnt = ecnt_ < ECAP ? ecnt_ : ECAP;                                 \
    gsrc = csr_src + ebase0;                                            \
    if (t_ < 32) {                                                      \
      int d_ = (blockBase + t_ < n_nodes) ? soff[t_ + 1] - soff[t_] : -1; \
      int r_ = 0;                                                       \
      for (int j_ = 0; j_ < 32; j_++) {                                 \
        int dj_ = (blockBase + j_ < n_nodes) ? soff[j_ + 1] - soff[j_] : -1; \
        if (dj_ > d_ || (dj_ == d_ && j_ < t_)) r_++;                   \
      }                                                                 \
      permAr[r_] = (u8)t_;                                              \
    }                                                                   \
    for (int e_ = t_; e_ < scnt; e_ += 256) eidx[e_] = gsrc[e_];        \
    __syncthreads();                                                    \
  }

#define IDX(i) ((i) < ECAP ? (int)eidx[i] : (int)gsrc[i])

// Half-row gather: each lane reads 8B (4 features) per edge. 8-deep = 64B
// in flight per lane (same as round-6's 4x16B). Summation tree per feature is
// BIT-IDENTICAL to round 6 (same edge order, same a0/a1 alternation).
#define ACC4(a, r) a[0] += bfpair(r.x); a[1] += bfpair(r.y);

#define GATHER_LOOP_HALF(h, eoff, ls, le, a0, a1)                            \
  {                                                                          \
    int i = ls;                                                              \
    for (; i + 7 < le; i += 8) {                                             \
      int s0 = IDX(i),     s1 = IDX(i + 1), s2 = IDX(i + 2), s3 = IDX(i + 3);\
      int s4 = IDX(i + 4), s5 = IDX(i + 5), s6 = IDX(i + 6), s7 = IDX(i + 7);\
      uint2 r0 = *(const uint2*)(h + ((size_t)s0 << 6) + (eoff));            \
      uint2 r1 = *(const uint2*)(h + ((size_t)s1 << 6) + (eoff));            \
      uint2 r2 = *(const uint2*)(h + ((size_t)s2 << 6) + (eoff));            \
      uint2 r3 = *(const uint2*)(h + ((size_t)s3 << 6) + (eoff));            \
      uint2 r4 = *(const uint2*)(h + ((size_t)s4 << 6) + (eoff));            \
      uint2 r5 = *(const uint2*)(h + ((size_t)s5 << 6) + (eoff));            \
      uint2 r6 = *(const uint2*)(h + ((size_t)s6 << 6) + (eoff));            \
      uint2 r7 = *(const uint2*)(h + ((size_t)s7 << 6) + (eoff));            \
      ACC4(a0, r0) ACC4(a1, r1) ACC4(a0, r2) ACC4(a1, r3)                    \
      ACC4(a0, r4) ACC4(a1, r5) ACC4(a0, r6) ACC4(a1, r7)                    \
    }                                                                        \
    for (; i + 3 < le; i += 4) {                                             \
      int s0 = IDX(i), s1 = IDX(i + 1), s2 = IDX(i + 2), s3 = IDX(i + 3);    \
      uint2 r0 = *(const uint2*)(h + ((size_t)s0 << 6) + (eoff));            \
      uint2 r1 = *(const uint2*)(h + ((size_t)s1 << 6) + (eoff));            \
      uint2 r2 = *(const uint2*)(h + ((size_t)s2 << 6) + (eoff));            \
      uint2 r3 = *(const uint2*)(h + ((size_t)s3 << 6) + (eoff));            \
      ACC4(a0, r0) ACC4(a1, r1) ACC4(a0, r2) ACC4(a1, r3)                    \
    }                                                                        \
    for (; i < le; i++) {                                                    \
      int s0 = IDX(i);                                                       \
      uint2 r0 = *(const uint2*)(h + ((size_t)s0 << 6) + (eoff));            \
      ACC4(a0, r0)                                                           \
    }                                                                        \
  }

// Soft pacing barrier: NO correctness role (h is read-only across passes).
// Bounded spin -> unconditionally deadlock-free even if not all blocks
// co-resident. No cache-flush semantics (unlike grid.sync, which cost 6.5x
// in round 7 by invalidating L2 across XCDs).
__device__ inline void soft_barrier(int* ctr, int nblk) {
  __syncthreads();
  if (threadIdx.x == 0) {
    atomicAdd(ctr, 1);
    int spins = 0;
    while (__hip_atomic_load(ctr, __ATOMIC_ACQUIRE, __HIP_MEMORY_SCOPE_AGENT) < nblk
           && spins < 20000) {
      __builtin_amdgcn_s_sleep(64);
      spins++;
    }
  }
  __syncthreads();
}

// ===========================================================================
// Fused layer (layers 1,2): 2-pass feature-split gather (pass p = features
// [p*32,(p+1)*32), per-pass working set 3.2MB < 4MB/XCD L2 -> repeats hit L2
// instead of streaming L3) -> LDS bf16 -> 4 waves x 8 MFMA -> bias/relu.
// ===========================================================================
__global__ __launch_bounds__(256) void fused_layer_kernel(
    const u16* __restrict__ h, const int* __restrict__ offsets,
    const u16* __restrict__ csr_src,
    const u16* __restrict__ WbTrel, const u16* __restrict__ WbTroot,
    const float* __restrict__ brel,
    u16* __restrict__ h_out, int n_nodes, int do_relu,
    int* __restrict__ bctr, int nblk) {
  __shared__ __align__(16) u16 ldsA[32 * 72];
  __shared__ __align__(16) u16 ldsX[32 * 72];
  __shared__ int soff[33];
  __shared__ u8 permAr[32];
  __shared__ u16 eidx[ECAP];
  int w = threadIdx.x >> 6;
  int lane = threadIdx.x & 63;
  int sub = lane >> 3;
  int flane = lane & 7;
  int blockBase = blockIdx.x * 32;
  const u16* gsrc;
  int ebase0, scnt;

  GATHER_PROLOGUE(soff, permAr, eidx, blockBase, n_nodes, offsets, csr_src, gsrc, ebase0, scnt)

  int ln = permAr[w * 8 + sub];
  int node = blockBase + ln;
  bool valid = node < n_nodes;
  int ls = soff[ln] - ebase0;
  int le = soff[ln + 1] - ebase0;
  if (!valid) le = ls;
  int lrow = ln * 72;

  // ---- pass 0: features [0,32) ----
  uint2 xr0 = make_uint2(0, 0);
  if (valid) xr0 = *(const uint2*)(h + ((size_t)node << 6) + flane * 4);
  *(uint2*)&ldsX[lrow + flane * 4] = xr0;

  f32x2 a0[2] = {{0,0},{0,0}}, a1[2] = {{0,0},{0,0}};
  GATHER_LOOP_HALF(h, flane * 4, ls, le, a0, a1)
  a0[0] += a1[0]; a0[1] += a1[1];
  uint2 pa0;
  pa0.x = (u32)f2bf(a0[0].x) | ((u32)f2bf(a0[0].y) << 16);
  pa0.y = (u32)f2bf(a0[1].x) | ((u32)f2bf(a0[1].y) << 16);
  *(uint2*)&ldsA[lrow + flane * 4] = pa0;

  soft_barrier(bctr, nblk);

  // ---- pass 1: features [32,64) ----
  uint2 xr1 = make_uint2(0, 0);
  if (valid) xr1 = *(const uint2*)(h + ((size_t)node << 6) + 32 + flane * 4);
  *(uint2*)&ldsX[lrow + 32 + flane * 4] = xr1;

  f32x2 b0[2] = {{0,0},{0,0}}, b1[2] = {{0,0},{0,0}};
  GATHER_LOOP_HALF(h, 32 + flane * 4, ls, le, b0, b1)
  b0[0] += b1[0]; b0[1] += b1[1];
  uint2 pa1;
  pa1.x = (u32)f2bf(b0[0].x) | ((u32)f2bf(b0[0].y) << 16);
  pa1.y = (u32)f2bf(b0[1].x) | ((u32)f2bf(b0[1].y) << 16);
  *(uint2*)&ldsA[lrow + 32 + flane * 4] = pa1;
  __syncthreads();

  // ---- MFMA dense phase: OUT[32x64] = A@Wrel + X@Wroot + b ----
  int mt = w & 1;
  int ntb = (w >> 1) * 2;
  int lr = lane & 15, lk = lane >> 4;
  int arow = (mt * 16 + lr) * 72;
  bf16x8 af0 = *(const bf16x8*)&ldsA[arow + lk * 8];
  bf16x8 af1 = *(const bf16x8*)&ldsA[arow + 32 + lk * 8];
  bf16x8 xf0 = *(const bf16x8*)&ldsX[arow + lk * 8];
  bf16x8 xf1 = *(const bf16x8*)&ldsX[arow + 32 + lk * 8];
#pragma unroll
  for (int tt = 0; tt < 2; tt++) {
    int nt = ntb + tt;
    int wrow = (nt * 16 + lr) * D + lk * 8;
    bf16x8 br0 = *(const bf16x8*)(WbTrel + wrow);
    bf16x8 br1 = *(const bf16x8*)(WbTrel + wrow + 32);
    bf16x8 bo0 = *(const bf16x8*)(WbTroot + wrow);
    bf16x8 bo1 = *(const bf16x8*)(WbTroot + wrow + 32);
    f32x4 acc = {0.0f, 0.0f, 0.0f, 0.0f};
    acc = __builtin_amdgcn_mfma_f32_16x16x32_bf16(af0, br0, acc, 0, 0, 0);
    acc = __builtin_amdgcn_mfma_f32_16x16x32_bf16(af1, br1, acc, 0, 0, 0);
    acc = __builtin_amdgcn_mfma_f32_16x16x32_bf16(xf0, bo0, acc, 0, 0, 0);
    acc = __builtin_amdgcn_mfma_f32_16x16x32_bf16(xf1, bo1, acc, 0, 0, 0);
    float bias = brel[nt * 16 + lr];
#pragma unroll
    for (int r = 0; r < 4; r++) {
      int onode = blockBase + mt * 16 + lk * 4 + r;
      if (onode < n_nodes) {
        float v = acc[r] + bias;
        if (do_relu) v = fmaxf(v, 0.0f);
        h_out[((size_t)onode << 6) + nt * 16 + lr] = f2bf(v);
      }
    }
  }
}

// ===========================================================================
// Layer 3 gather + pool: same 2-pass feature-split; block-level run-length
// reduction over sorted graph ids -> ~1 atomic per (graph,feature) run.
// ===========================================================================
__global__ __launch_bounds__(256) void gather_pool_kernel(
    const u16* __restrict__ h, const int* __restrict__ offsets,
    const u16* __restrict__ csr_src, const int* __restrict__ batch,
    float* __restrict__ pooledA, float* __restrict__ pooledH, int n_nodes,
    int* __restrict__ bctr, int nblk) {
  __shared__ int soff[33];
  __shared__ u8 permAr[32];
  __shared__ u16 eidx[ECAP];
  __shared__ int gid[32];
  __shared__ float ldsPA[32][D];
  __shared__ float ldsPH[32][D];
  int w = threadIdx.x >> 6;
  int lane = threadIdx.x & 63;
  int sub = lane >> 3;
  int flane = lane & 7;
  int blockBase = blockIdx.x * 32;
  if (threadIdx.x < 32)
    gid[threadIdx.x] = (blockBase + threadIdx.x < n_nodes) ? batch[blockBase + threadIdx.x] : -1;
  const u16* gsrc;
  int ebase0, scnt;

  GATHER_PROLOGUE(soff, permAr, eidx, blockBase, n_nodes, offsets, csr_src, gsrc, ebase0, scnt)

  int ln = permAr[w * 8 + sub];
  int node = blockBase + ln;
  bool valid = node < n_nodes;
  int ls = soff[ln] - ebase0;
  int le = soff[ln + 1] - ebase0;
  if (!valid) le = ls;

  // ---- pass 0: features [0,32) ----
  uint2 xr0 = make_uint2(0, 0);
  if (valid) xr0 = *(const uint2*)(h + ((size_t)node << 6) + flane * 4);
  f32x2 a0[2] = {{0,0},{0,0}}, a1[2] = {{0,0},{0,0}};
  GATHER_LOOP_HALF(h, flane * 4, ls, le, a0, a1)
  a0[0] += a1[0]; a0[1] += a1[1];
  {
    f32x2 x0 = bfpair(xr0.x), x1 = bfpair(xr0.y);
    float* rowA = &ldsPA[ln][flane * 4];
    float* rowH = &ldsPH[ln][flane * 4];
    rowA[0] = a0[0].x; rowA[1] = a0[0].y; rowA[2] = a0[1].x; rowA[3] = a0[1].y;
    rowH[0] = x0.x; rowH[1] = x0.y; rowH[2] = x1.x; rowH[3] = x1.y;
  }

  soft_barrier(bctr, nblk);

  // ---- pass 1: features [32,64) ----
  uint2 xr1 = make_uint2(0, 0);
  if (valid) xr1 = *(const uint2*)(h + ((size_t)node << 6) + 32 + flane * 4);
  f32x2 b0[2] = {{0,0},{0,0}}, b1[2] = {{0,0},{0,0}};
  GATHER_LOOP_HALF(h, 32 + flane * 4, ls, le, b0, b1)
  b0[0] += b1[0]; b0[1] += b1[1];
  {
    f32x2 x0 = bfpair(xr1.x), x1 = bfpair(xr1.y);
    float* rowA = &ldsPA[ln][32 + flane * 4];
    float* rowH = &ldsPH[ln][32 + flane * 4];
    rowA[0] = b0[0].x; rowA[1] = b0[0].y; rowA[2] = b0[1].x; rowA[3] = b0[1].y;
    rowH[0] = x0.x; rowH[1] = x0.y; rowH[2] = x1.x; rowH[3] = x1.y;
  }
  __syncthreads();

  if (threadIdx.x < 128) {
    int half = threadIdx.x >> 6;
    int f = threadIdx.x & 63;
    float* dst = half ? pooledH : pooledA;
    float acc = 0.0f;
    int curg = -1;
#pragma unroll 1
    for (int n = 0; n < 32; n++) {
      int g = gid[n];
      if (g < 0) break;
      float v = half ? ldsPH[n][f] : ldsPA[n][f];
      if (g != curg) {
        if (curg >= 0) atomicAdd(dst + curg * D + f, acc);
        curg = g;
        acc = v;
      } else {
        acc += v;
      }
    }
    if (curg >= 0) atomicAdd(dst + curg * D + f, acc);
  }
}

// out[g,o] = meanA@M1 + meanH@M2 + cvec  (blin if graph empty).
__global__ __launch_bounds__(64) void final_kernel(
    const float* __restrict__ pooledA, const float* __restrict__ pooledH,
    const float* __restrict__ M1, const float* __restrict__ M2,
    const float* __restrict__ cvec, const float* __restrict__ blin,
    const int* __restrict__ batch, float* __restrict__ out, int n_nodes) {
  __shared__ int seg[2];
  int g = blockIdx.x;
  int t = threadIdx.x;
  if (t < 2) {
    int target = g + t;
    int lo = 0, hi = n_nodes;
    while (lo < hi) {
      int mid = (lo + hi) >> 1;
      if (batch[mid] < target) lo = mid + 1; else hi = mid;
    }
    seg[t] = lo;
  }
  __syncthreads();
  int cnt = seg[1] - seg[0];
  if (t < D_OUT) {
    float res;
    if (cnt > 0) {
      float inv = 1.0f / (float)cnt;
      float acc = cvec[t];
#pragma unroll
      for (int k = 0; k < D; k++)
        acc = fmaf(pooledA[g * D + k] * inv, M1[k * D_OUT + t],
              fmaf(pooledH[g * D + k] * inv, M2[k * D_OUT + t], acc));
      res = acc;
    } else {
      res = blin[t];
    }
    out[g * D_OUT + t] = res;
  }
}

extern "C" void kernel_launch(void* const* d_in, const int* in_sizes, int n_in,
                              void* d_out, int out_size, void* d_ws, size_t ws_size,
                              hipStream_t stream) {
  const float* x     = (const float*)d_in[0];
  const int*   ei    = (const int*)d_in[1];
  const int*   batch = (const int*)d_in[3];
  const float* Wrel1 = (const float*)d_in[4];
  const float* brel1 = (const float*)d_in[5];
  const float* Wroot1= (const float*)d_in[6];
  const float* Wrel2 = (const float*)d_in[7];
  const float* brel2 = (const float*)d_in[8];
  const float* Wroot2= (const float*)d_in[9];
  const float* Wrel3 = (const float*)d_in[10];
  const float* brel3 = (const float*)d_in[11];
  const float* Wroot3= (const float*)d_in[12];
  const float* Wlin  = (const float*)d_in[13];
  const float* blin  = (const float*)d_in[14];
  float* out = (float*)d_out;

  const int n_edges = in_sizes[1] / 2;
  const int n_nodes = in_sizes[0] / D;
  const int* src = ei;
  const int* dst = ei + n_edges;
  const int nbuck = (n_nodes + 255) >> 8;  // 196

  // ---- workspace carve-up ----
  char* p = (char*)d_ws;
  u32* binned  = (u32*)p;    p += (size_t)nbuck * BCAP * sizeof(u32);
  int* cursors = (int*)p;    p += 256 * sizeof(int);                   // memset zone start
  float* pooledA = (float*)p; p += (size_t)N_GRAPHS * D * sizeof(float);
  float* pooledH = (float*)p; p += (size_t)N_GRAPHS * D * sizeof(float);
  int* bctr    = (int*)p;    p += 4 * sizeof(int);                     // memset zone end
  float* M1     = (float*)p; p += (size_t)D * D_OUT * sizeof(float);
  float* M2     = (float*)p; p += (size_t)D * D_OUT * sizeof(float);
  float* cvec   = (float*)p; p += 16 * sizeof(float);
  int* offsets  = (int*)p;   p += (size_t)(n_nodes + 4) * sizeof(int);
  u16* hX       = (u16*)p;   p += (size_t)n_nodes * D * sizeof(u16);
  u16* h1       = (u16*)p;   p += (size_t)n_nodes * D * sizeof(u16);
  u16* h2       = (u16*)p;   p += (size_t)n_nodes * D * sizeof(u16);
  u16* csr_src  = (u16*)p;   p += (size_t)n_edges * sizeof(u16);
  u16* WbT1r    = (u16*)p;   p += (size_t)D * D * sizeof(u16);
  u16* WbT1o    = (u16*)p;   p += (size_t)D * D * sizeof(u16);
  u16* WbT2r    = (u16*)p;   p += (size_t)D * D * sizeof(u16);
  u16* WbT2o    = (u16*)p;   p += (size_t)D * D * sizeof(u16);

  const int bin_blocks = (n_edges + TILE - 1) / TILE;   // 306
  const int cvt_n4 = n_nodes * D / 4;
  const int cvt_blocks = (cvt_n4 + 255) / 256;          // 3125
  const int fused_blocks = (n_nodes + 31) / 32;         // 1563

  const size_t zero_bytes = 256 * sizeof(int)
      + 2 * (size_t)N_GRAPHS * D * sizeof(float) + 4 * sizeof(int);
  hipMemsetAsync(cursors, 0, zero_bytes, stream);

  cvtbin_kernel<<<bin_blocks + cvt_blocks, 256, 0, stream>>>(
      x, hX, cvt_n4, bin_blocks, src, dst, cursors, binned, n_edges, nbuck,
      Wrel1, Wroot1, Wrel2, Wroot2, Wrel3, Wroot3, Wlin, brel3, blin,
      M1, M2, cvec, WbT1r, WbT1o, WbT2r, WbT2o);
  csr_kernel<<<nbuck, 256, 0, stream>>>(binned, cursors, csr_src, offsets, n_nodes, nbuck);

  fused_layer_kernel<<<fused_blocks, 256, 0, stream>>>(
      hX, offsets, csr_src, WbT1r, WbT1o, brel1, h1, n_nodes, 1,
      bctr + 0, fused_blocks);
  fused_layer_kernel<<<fused_blocks, 256, 0, stream>>>(
      h1, offsets, csr_src, WbT2r, WbT2o, brel2, h2, n_nodes, 1,
      bctr + 1, fused_blocks);

  gather_pool_kernel<<<fused_blocks, 256, 0, stream>>>(
      h2, offsets, csr_src, batch, pooledA, pooledH, n_nodes,
      bctr + 2, fused_blocks);

  final_kernel<<<N_GRAPHS, 64, 0, stream>>>(
      pooledA, pooledH, M1, M2, cvec, blin, batch, out, n_nodes);
}

// Round 10
// 219.672 us; speedup vs baseline: 4.0069x; 4.0069x over previous
//
#include <hip/hip_runtime.h>

#define D 64
#define N_GRAPHS 128
#define D_OUT 16
#define BCAP 16384   // max edges per 256-node bucket (avg 6400, sigma ~80)
#define TILE 4096    // edges per bin_kernel block
#define ECAP 2048    // max edges per 32-node block staged in LDS (avg 800)

typedef unsigned short u16;
typedef unsigned int u32;
typedef unsigned char u8;
typedef __attribute__((ext_vector_type(8))) short bf16x8;
typedef __attribute__((ext_vector_type(4))) float f32x4;
typedef __attribute__((ext_vector_type(2))) float f32x2;

__device__ inline u16 f2bf(float f) {  // round-to-nearest-even
  u32 u = __float_as_uint(f);
  return (u16)((u + 0x7fffu + ((u >> 16) & 1u)) >> 16);
}
__device__ inline float bf2f(u16 b) { return __uint_as_float((u32)b << 16); }
__device__ inline f32x2 bfpair(u32 v) {
  return (f32x2){__uint_as_float(v << 16), __uint_as_float(v & 0xffff0000u)};
}

// ===========================================================================
// Merged front-end: blocks [0,nbin) = edge binning; blocks [nbin,...) =
// x->bf16 convert + weight precompute (overlap on CU array). cursors pre-zeroed.
// ===========================================================================
__global__ __launch_bounds__(256) void cvtbin_kernel(
    const float* __restrict__ xin, u16* __restrict__ hX, int n4, int nbin,
    const int* __restrict__ src, const int* __restrict__ dst,
    int* __restrict__ cursors, u32* __restrict__ binned, int n_edges, int nbuck,
    const float* __restrict__ Wrel1, const float* __restrict__ Wroot1,
    const float* __restrict__ Wrel2, const float* __restrict__ Wroot2,
    const float* __restrict__ Wrel3, const float* __restrict__ Wroot3,
    const float* __restrict__ Wlin, const float* __restrict__ brel3,
    const float* __restrict__ blin,
    float* __restrict__ M1, float* __restrict__ M2, float* __restrict__ cvec,
    u16* __restrict__ WbT1r, u16* __restrict__ WbT1o,
    u16* __restrict__ WbT2r, u16* __restrict__ WbT2o) {
  __shared__ u32 ent[TILE];
  __shared__ u8 ebk[TILE];
  __shared__ int hist[256];
  __shared__ int startb[256];
  __shared__ int cur[256];
  __shared__ int gbase[256];
  int t = threadIdx.x;

  if ((int)blockIdx.x < nbin) {
    hist[t] = 0;
    __syncthreads();
    int base = blockIdx.x * TILE;
    int cnt = n_edges - base;
    if (cnt > TILE) cnt = TILE;

    int mys[16], myd[16];
#pragma unroll
    for (int j = 0; j < 16; j++) {
      int i = base + t + j * 256;
      if (t + j * 256 < cnt) {
        mys[j] = src[i];
        myd[j] = dst[i];
        atomicAdd(&hist[myd[j] >> 8], 1);
      } else {
        myd[j] = -1;
      }
    }
    __syncthreads();
    int myc = hist[t];
    for (int off = 1; off < 256; off <<= 1) {
      int tmp = (t >= off) ? hist[t - off] : 0;
      __syncthreads();
      hist[t] += tmp;
      __syncthreads();
    }
    int excl = hist[t] - myc;
    startb[t] = excl;
    cur[t] = excl;
    __syncthreads();

#pragma unroll
    for (int j = 0; j < 16; j++) {
      if (myd[j] >= 0) {
        int b = myd[j] >> 8;
        int p = atomicAdd(&cur[b], 1);
        ent[p] = ((u32)myd[j] << 16) | (u32)mys[j];
        ebk[p] = (u8)b;
      }
    }
    __syncthreads();

    if (t < nbuck && myc > 0) gbase[t] = atomicAdd(&cursors[t], myc);
    __syncthreads();

#pragma unroll
    for (int j = 0; j < 16; j++) {
      int p = t + j * 256;
      if (p < cnt) {
        int b = ebk[p];
        int gpos = gbase[b] + (p - startb[b]);
        if (gpos < BCAP) binned[(size_t)b * BCAP + gpos] = ent[p];
      }
    }
    return;
  }

  int cb = blockIdx.x - nbin;
  if (cb == 0) {
    if (t >= 240) {
      int o = t - 240;
      float c = blin[o];
#pragma unroll
      for (int j = 0; j < D; j++) c = fmaf(brel3[j], Wlin[j * D_OUT + o], c);
      cvec[o] = c;
    }
  } else if (cb <= 8) {
    int idx = (cb - 1) * 256 + t;
    const float* W = (idx < 1024) ? Wrel3 : Wroot3;
    float* M = (idx < 1024) ? M1 : M2;
    int id = idx & 1023;
    int k = id >> 4, o = id & 15;
    float acc = 0.0f;
#pragma unroll
    for (int j = 0; j < D; j++) acc = fmaf(W[k * D + j], Wlin[j * D_OUT + o], acc);
    M[id] = acc;
  } else if (cb <= 16) {
    int tid = (cb - 9) * 256 + t;
    int mat = tid >> 9;
    int r = tid & 511;
    int o = r >> 3;
    int k0 = (r & 7) * 8;
    const float* Wsrc = (mat == 0) ? Wrel1 : (mat == 1) ? Wroot1
                       : (mat == 2) ? Wrel2 : Wroot2;
    u16* Wdst = (mat == 0) ? WbT1r : (mat == 1) ? WbT1o
               : (mat == 2) ? WbT2r : WbT2o;
    u16 tmp[8];
#pragma unroll
    for (int j = 0; j < 8; j++) tmp[j] = f2bf(Wsrc[(k0 + j) * D + o]);
    uint4 pw;
    pw.x = (u32)tmp[0] | ((u32)tmp[1] << 16);
    pw.y = (u32)tmp[2] | ((u32)tmp[3] << 16);
    pw.z = (u32)tmp[4] | ((u32)tmp[5] << 16);
    pw.w = (u32)tmp[6] | ((u32)tmp[7] << 16);
    *(uint4*)&Wdst[o * D + k0] = pw;
  }
  int i = cb * 256 + t;
  if (i >= n4) return;
  float4 v = ((const float4*)xin)[i];
  ushort4 o4;
  o4.x = f2bf(v.x); o4.y = f2bf(v.y); o4.z = f2bf(v.z); o4.w = f2bf(v.w);
  ((ushort4*)hX)[i] = o4;
}

// ===========================================================================
// CSR pass 2 v3: per-node segments PARTITIONED by src half [low | high].
// midoff[n] = split point. Gathers then do 2 sub-passes, each touching a
// 3.2MB row region that FITS the 4MB per-XCD L2 (full 128B lines this time;
// round 9's feature split failed because half-line reads still fill whole
// lines). No barrier: all 1563 blocks co-resident, naturally phase-aligned.
// ===========================================================================
__global__ __launch_bounds__(256) void csr_kernel(
    const u32* __restrict__ binned, const int* __restrict__ cursors,
    u16* __restrict__ csr_src, int* __restrict__ offsets,
    int* __restrict__ midoff, int n_nodes, int nbuck, int halfThresh) {
  __shared__ int deg2[512];   // [node][half]
  __shared__ int cur2[512];
  __shared__ int red[256];
  __shared__ u16 lcsr[BCAP];
  int b = blockIdx.x, t = threadIdx.x;
  int cnt = cursors[b];
  if (cnt < 0) cnt = 0;
  if (cnt > BCAP) cnt = BCAP;

  // ebase = sum of counts of buckets < b
  int c = 0;
  if (t < b) {
    c = cursors[t];
    if (c < 0) c = 0;
    if (c > BCAP) c = BCAP;
  }
  red[t] = c;
  __syncthreads();
  for (int off = 128; off > 0; off >>= 1) {
    if (t < off) red[t] += red[t + off];
    __syncthreads();
  }
  int ebase = red[0];

  int nodeBase = b << 8;
  int nn = n_nodes - nodeBase;
  if (nn > 256) nn = 256;

  deg2[t] = 0;
  deg2[t + 256] = 0;
  __syncthreads();
  const u32* be = binned + (size_t)b * BCAP;
  for (int i = t; i < cnt; i += 256) {
    u32 e = be[i];
    int ln = (e >> 16) - nodeBase;
    int half = ((int)(e & 0xffffu) >= halfThresh) ? 1 : 0;
    atomicAdd(&deg2[ln * 2 + half], 1);
  }
  __syncthreads();
  int lowc = deg2[t * 2], highc = deg2[t * 2 + 1];
  int myTotal = lowc + highc;
  // inclusive scan of per-node totals
  red[t] = myTotal;
  __syncthreads();
  for (int off = 1; off < 256; off <<= 1) {
    int tmp = (t >= off) ? red[t - off] : 0;
    __syncthreads();
    red[t] += tmp;
    __syncthreads();
  }
  int excl = red[t] - myTotal;
  cur2[t * 2] = excl;
  cur2[t * 2 + 1] = excl + lowc;
  if (t < nn) {
    offsets[nodeBase + t] = ebase + excl;
    midoff[nodeBase + t] = ebase + excl + lowc;
  }
  if (b == nbuck - 1 && t == 0) offsets[n_nodes] = ebase + cnt;
  __syncthreads();

  for (int i = t; i < cnt; i += 256) {
    u32 e = be[i];
    int ln = (e >> 16) - nodeBase;
    int half = ((int)(e & 0xffffu) >= halfThresh) ? 1 : 0;
    int p = atomicAdd(&cur2[ln * 2 + half], 1);
    lcsr[p] = (u16)(e & 0xffffu);
  }
  __syncthreads();
  for (int i = t; i < cnt; i += 256) csr_src[ebase + i] = lcsr[i];
}

#define ACC8(a, r) \
  a[0] += bfpair(r.x); a[1] += bfpair(r.y); a[2] += bfpair(r.z); a[3] += bfpair(r.w);

// Prologue: soff/smid -> LDS, degree-rank perm, contiguous csr run -> LDS.
#define GATHER_PROLOGUE(soff, smid, permAr, eidx, blockBase, n_nodes, offsets, midoff, csr_src, gsrc, ebase0, scnt) \
  {                                                                     \
    int t_ = threadIdx.x;                                               \
    if (t_ < 33) {                                                      \
      int idx = blockBase + t_;                                         \
      if (idx > n_nodes) idx = n_nodes;                                 \
      soff[t_] = offsets[idx];                                          \
    }                                                                   \
    if (t_ >= 64 && t_ < 96) {                                          \
      int n_ = t_ - 64;                                                 \
      int idx = blockBase + n_;                                         \
      smid[n_] = (idx < n_nodes) ? midoff[idx] : 0;                     \
    }                                                                   \
    __syncthreads();                                                    \
    ebase0 = soff[0];                                                   \
    int ecnt_ = soff[32] - ebase0;                                      \
    scnt = ecnt_ < ECAP ? ecnt_ : ECAP;                                 \
    gsrc = csr_src + ebase0;                                            \
    if (t_ < 32) {                                                      \
      int d_ = (blockBase + t_ < n_nodes) ? soff[t_ + 1] - soff[t_] : -1; \
      int r_ = 0;                                                       \
      for (int j_ = 0; j_ < 32; j_++) {                                 \
        int dj_ = (blockBase + j_ < n_nodes) ? soff[j_ + 1] - soff[j_] : -1; \
        if (dj_ > d_ || (dj_ == d_ && j_ < t_)) r_++;                   \
      }                                                                 \
      permAr[r_] = (u8)t_;                                              \
    }                                                                   \
    for (int e_ = t_; e_ < scnt; e_ += 256) eidx[e_] = gsrc[e_];        \
    __syncthreads();                                                    \
  }

#define IDX(i) ((i) < ECAP ? (int)eidx[i] : (int)gsrc[i])

// 4-deep unrolled gather body (round-6 config), full 16B row reads.
#define GATHER_LOOP(h, fo, ls, le, a0, a1)                                   \
  {                                                                          \
    int i = ls;                                                              \
    for (; i + 3 < le; i += 4) {                                             \
      int s0 = IDX(i), s1 = IDX(i + 1), s2 = IDX(i + 2), s3 = IDX(i + 3);    \
      uint4 r0 = *(const uint4*)(h + ((size_t)s0 << 6) + fo);                \
      uint4 r1 = *(const uint4*)(h + ((size_t)s1 << 6) + fo);                \
      uint4 r2 = *(const uint4*)(h + ((size_t)s2 << 6) + fo);                \
      uint4 r3 = *(const uint4*)(h + ((size_t)s3 << 6) + fo);                \
      ACC8(a0, r0) ACC8(a1, r1) ACC8(a0, r2) ACC8(a1, r3)                    \
    }                                                                        \
    for (; i < le; i++) {                                                    \
      int s0 = IDX(i);                                                       \
      uint4 r0 = *(const uint4*)(h + ((size_t)s0 << 6) + fo);                \
      ACC8(a0, r0)                                                           \
    }                                                                        \
  }

// ===========================================================================
// Fused layer (layers 1,2): 2 sub-passes over src halves (L2-blocked) ->
// LDS bf16 -> 4 waves x 8 mfma_f32_16x16x32_bf16 -> bias/relu -> h_out.
// ===========================================================================
__global__ __launch_bounds__(256) void fused_layer_kernel(
    const u16* __restrict__ h, const int* __restrict__ offsets,
    const int* __restrict__ midoff, const u16* __restrict__ csr_src,
    const u16* __restrict__ WbTrel, const u16* __restrict__ WbTroot,
    const float* __restrict__ brel,
    u16* __restrict__ h_out, int n_nodes, int do_relu) {
  __shared__ __align__(16) u16 ldsA[32 * 72];
  __shared__ __align__(16) u16 ldsX[32 * 72];
  __shared__ int soff[33];
  __shared__ int smid[32];
  __shared__ u8 permAr[32];
  __shared__ u16 eidx[ECAP];
  int w = threadIdx.x >> 6;
  int lane = threadIdx.x & 63;
  int sub = lane >> 3;
  int fo = (lane & 7) * 8;
  int blockBase = blockIdx.x * 32;
  const u16* gsrc;
  int ebase0, scnt;

  GATHER_PROLOGUE(soff, smid, permAr, eidx, blockBase, n_nodes, offsets, midoff, csr_src, gsrc, ebase0, scnt)

  int ln = permAr[w * 8 + sub];
  int node = blockBase + ln;
  bool valid = node < n_nodes;
  int ls = soff[ln] - ebase0;
  int le = soff[ln + 1] - ebase0;
  if (!valid) le = ls;
  int lm = valid ? smid[ln] - ebase0 : ls;
  if (lm < ls) lm = ls;
  if (lm > le) lm = le;
  int lrow = ln * 72;

  uint4 xr = make_uint4(0, 0, 0, 0);
  if (valid) xr = *(const uint4*)(h + ((size_t)node << 6) + fo);
  *(uint4*)&ldsX[lrow + fo] = xr;

  f32x2 a0[4] = {{0,0},{0,0},{0,0},{0,0}};
  f32x2 a1[4] = {{0,0},{0,0},{0,0},{0,0}};
  // pass A: src rows [0, halfThresh) — 3.2MB region, L2-resident
  GATHER_LOOP(h, fo, ls, lm, a0, a1)
  // pass B: src rows [halfThresh, n_nodes)
  GATHER_LOOP(h, fo, lm, le, a0, a1)
#pragma unroll
  for (int k = 0; k < 4; k++) a0[k] += a1[k];

  uint4 pa;
  pa.x = (u32)f2bf(a0[0].x) | ((u32)f2bf(a0[0].y) << 16);
  pa.y = (u32)f2bf(a0[1].x) | ((u32)f2bf(a0[1].y) << 16);
  pa.z = (u32)f2bf(a0[2].x) | ((u32)f2bf(a0[2].y) << 16);
  pa.w = (u32)f2bf(a0[3].x) | ((u32)f2bf(a0[3].y) << 16);
  *(uint4*)&ldsA[lrow + fo] = pa;
  __syncthreads();

  // ---- MFMA dense phase: OUT[32x64] = A@Wrel + X@Wroot + b ----
  int mt = w & 1;
  int ntb = (w >> 1) * 2;
  int lr = lane & 15, lk = lane >> 4;
  int arow = (mt * 16 + lr) * 72;
  bf16x8 af0 = *(const bf16x8*)&ldsA[arow + lk * 8];
  bf16x8 af1 = *(const bf16x8*)&ldsA[arow + 32 + lk * 8];
  bf16x8 xf0 = *(const bf16x8*)&ldsX[arow + lk * 8];
  bf16x8 xf1 = *(const bf16x8*)&ldsX[arow + 32 + lk * 8];
#pragma unroll
  for (int tt = 0; tt < 2; tt++) {
    int nt = ntb + tt;
    int wrow = (nt * 16 + lr) * D + lk * 8;
    bf16x8 br0 = *(const bf16x8*)(WbTrel + wrow);
    bf16x8 br1 = *(const bf16x8*)(WbTrel + wrow + 32);
    bf16x8 bo0 = *(const bf16x8*)(WbTroot + wrow);
    bf16x8 bo1 = *(const bf16x8*)(WbTroot + wrow + 32);
    f32x4 acc = {0.0f, 0.0f, 0.0f, 0.0f};
    acc = __builtin_amdgcn_mfma_f32_16x16x32_bf16(af0, br0, acc, 0, 0, 0);
    acc = __builtin_amdgcn_mfma_f32_16x16x32_bf16(af1, br1, acc, 0, 0, 0);
    acc = __builtin_amdgcn_mfma_f32_16x16x32_bf16(xf0, bo0, acc, 0, 0, 0);
    acc = __builtin_amdgcn_mfma_f32_16x16x32_bf16(xf1, bo1, acc, 0, 0, 0);
    float bias = brel[nt * 16 + lr];
#pragma unroll
    for (int r = 0; r < 4; r++) {
      int onode = blockBase + mt * 16 + lk * 4 + r;
      if (onode < n_nodes) {
        float v = acc[r] + bias;
        if (do_relu) v = fmaxf(v, 0.0f);
        h_out[((size_t)onode << 6) + nt * 16 + lr] = f2bf(v);
      }
    }
  }
}

// ===========================================================================
// Layer 3 gather + pool: same 2 sub-pass gather; block-level run-length
// reduction over sorted graph ids -> ~1 atomic per (graph,feature) run.
// ===========================================================================
__global__ __launch_bounds__(256) void gather_pool_kernel(
    const u16* __restrict__ h, const int* __restrict__ offsets,
    const int* __restrict__ midoff, const u16* __restrict__ csr_src,
    const int* __restrict__ batch,
    float* __restrict__ pooledA, float* __restrict__ pooledH, int n_nodes) {
  __shared__ int soff[33];
  __shared__ int smid[32];
  __shared__ u8 permAr[32];
  __shared__ u16 eidx[ECAP];
  __shared__ int gid[32];
  __shared__ float ldsPA[32][D];
  __shared__ float ldsPH[32][D];
  int w = threadIdx.x >> 6;
  int lane = threadIdx.x & 63;
  int sub = lane >> 3;
  int fo = (lane & 7) * 8;
  int blockBase = blockIdx.x * 32;
  if (threadIdx.x < 32)
    gid[threadIdx.x] = (blockBase + threadIdx.x < n_nodes) ? batch[blockBase + threadIdx.x] : -1;
  const u16* gsrc;
  int ebase0, scnt;

  GATHER_PROLOGUE(soff, smid, permAr, eidx, blockBase, n_nodes, offsets, midoff, csr_src, gsrc, ebase0, scnt)

  int ln = permAr[w * 8 + sub];
  int node = blockBase + ln;
  bool valid = node < n_nodes;
  int ls = soff[ln] - ebase0;
  int le = soff[ln + 1] - ebase0;
  if (!valid) le = ls;
  int lm = valid ? smid[ln] - ebase0 : ls;
  if (lm < ls) lm = ls;
  if (lm > le) lm = le;

  f32x2 a0[4] = {{0,0},{0,0},{0,0},{0,0}};
  f32x2 a1[4] = {{0,0},{0,0},{0,0},{0,0}};
  GATHER_LOOP(h, fo, ls, lm, a0, a1)
  GATHER_LOOP(h, fo, lm, le, a0, a1)
#pragma unroll
  for (int k = 0; k < 4; k++) a0[k] += a1[k];

  uint4 xr = make_uint4(0, 0, 0, 0);
  if (valid) xr = *(const uint4*)(h + ((size_t)node << 6) + fo);
  f32x2 x0 = bfpair(xr.x), x1 = bfpair(xr.y), x2 = bfpair(xr.z), x3 = bfpair(xr.w);
  float* rowA = &ldsPA[ln][fo];
  float* rowH = &ldsPH[ln][fo];
  rowA[0] = a0[0].x; rowA[1] = a0[0].y; rowA[2] = a0[1].x; rowA[3] = a0[1].y;
  rowA[4] = a0[2].x; rowA[5] = a0[2].y; rowA[6] = a0[3].x; rowA[7] = a0[3].y;
  rowH[0] = x0.x; rowH[1] = x0.y; rowH[2] = x1.x; rowH[3] = x1.y;
  rowH[4] = x2.x; rowH[5] = x2.y; rowH[6] = x3.x; rowH[7] = x3.y;
  __syncthreads();

  if (threadIdx.x < 128) {
    int half = threadIdx.x >> 6;
    int f = threadIdx.x & 63;
    float* dst = half ? pooledH : pooledA;
    float acc = 0.0f;
    int curg = -1;
#pragma unroll 1
    for (int n = 0; n < 32; n++) {
      int g = gid[n];
      if (g < 0) break;
      float v = half ? ldsPH[n][f] : ldsPA[n][f];
      if (g != curg) {
        if (curg >= 0) atomicAdd(dst + curg * D + f, acc);
        curg = g;
        acc = v;
      } else {
        acc += v;
      }
    }
    if (curg >= 0) atomicAdd(dst + curg * D + f, acc);
  }
}

// out[g,o] = meanA@M1 + meanH@M2 + cvec  (blin if graph empty).
__global__ __launch_bounds__(64) void final_kernel(
    const float* __restrict__ pooledA, const float* __restrict__ pooledH,
    const float* __restrict__ M1, const float* __restrict__ M2,
    const float* __restrict__ cvec, const float* __restrict__ blin,
    const int* __restrict__ batch, float* __restrict__ out, int n_nodes) {
  __shared__ int seg[2];
  int g = blockIdx.x;
  int t = threadIdx.x;
  if (t < 2) {
    int target = g + t;
    int lo = 0, hi = n_nodes;
    while (lo < hi) {
      int mid = (lo + hi) >> 1;
      if (batch[mid] < target) lo = mid + 1; else hi = mid;
    }
    seg[t] = lo;
  }
  __syncthreads();
  int cnt = seg[1] - seg[0];
  if (t < D_OUT) {
    float res;
    if (cnt > 0) {
      float inv = 1.0f / (float)cnt;
      float acc = cvec[t];
#pragma unroll
      for (int k = 0; k < D; k++)
        acc = fmaf(pooledA[g * D + k] * inv, M1[k * D_OUT + t],
              fmaf(pooledH[g * D + k] * inv, M2[k * D_OUT + t], acc));
      res = acc;
    } else {
      res = blin[t];
    }
    out[g * D_OUT + t] = res;
  }
}

extern "C" void kernel_launch(void* const* d_in, const int* in_sizes, int n_in,
                              void* d_out, int out_size, void* d_ws, size_t ws_size,
                              hipStream_t stream) {
  const float* x     = (const float*)d_in[0];
  const int*   ei    = (const int*)d_in[1];
  const int*   batch = (const int*)d_in[3];
  const float* Wrel1 = (const float*)d_in[4];
  const float* brel1 = (const float*)d_in[5];
  const float* Wroot1= (const float*)d_in[6];
  const float* Wrel2 = (const float*)d_in[7];
  const float* brel2 = (const float*)d_in[8];
  const float* Wroot2= (const float*)d_in[9];
  const float* Wrel3 = (const float*)d_in[10];
  const float* brel3 = (const float*)d_in[11];
  const float* Wroot3= (const float*)d_in[12];
  const float* Wlin  = (const float*)d_in[13];
  const float* blin  = (const float*)d_in[14];
  float* out = (float*)d_out;

  const int n_edges = in_sizes[1] / 2;
  const int n_nodes = in_sizes[0] / D;
  const int* src = ei;
  const int* dst = ei + n_edges;
  const int nbuck = (n_nodes + 255) >> 8;  // 196
  const int halfThresh = n_nodes / 2;

  // ---- workspace carve-up ----
  char* p = (char*)d_ws;
  u32* binned  = (u32*)p;    p += (size_t)nbuck * BCAP * sizeof(u32);
  int* cursors = (int*)p;    p += 256 * sizeof(int);                   // memset zone start
  float* pooledA = (float*)p; p += (size_t)N_GRAPHS * D * sizeof(float);
  float* pooledH = (float*)p; p += (size_t)N_GRAPHS * D * sizeof(float); // memset zone end
  float* M1     = (float*)p; p += (size_t)D * D_OUT * sizeof(float);
  float* M2     = (float*)p; p += (size_t)D * D_OUT * sizeof(float);
  float* cvec   = (float*)p; p += 16 * sizeof(float);
  int* offsets  = (int*)p;   p += (size_t)(n_nodes + 4) * sizeof(int);
  int* midoff   = (int*)p;   p += (size_t)(n_nodes + 4) * sizeof(int);
  u16* hX       = (u16*)p;   p += (size_t)n_nodes * D * sizeof(u16);
  u16* h1       = (u16*)p;   p += (size_t)n_nodes * D * sizeof(u16);
  u16* h2       = (u16*)p;   p += (size_t)n_nodes * D * sizeof(u16);
  u16* csr_src  = (u16*)p;   p += (size_t)n_edges * sizeof(u16);
  u16* WbT1r    = (u16*)p;   p += (size_t)D * D * sizeof(u16);
  u16* WbT1o    = (u16*)p;   p += (size_t)D * D * sizeof(u16);
  u16* WbT2r    = (u16*)p;   p += (size_t)D * D * sizeof(u16);
  u16* WbT2o    = (u16*)p;   p += (size_t)D * D * sizeof(u16);

  const int bin_blocks = (n_edges + TILE - 1) / TILE;   // 306
  const int cvt_n4 = n_nodes * D / 4;
  const int cvt_blocks = (cvt_n4 + 255) / 256;          // 3125
  const int fused_blocks = (n_nodes + 31) / 32;         // 1563

  const size_t zero_bytes = 256 * sizeof(int) + 2 * (size_t)N_GRAPHS * D * sizeof(float);
  hipMemsetAsync(cursors, 0, zero_bytes, stream);

  cvtbin_kernel<<<bin_blocks + cvt_blocks, 256, 0, stream>>>(
      x, hX, cvt_n4, bin_blocks, src, dst, cursors, binned, n_edges, nbuck,
      Wrel1, Wroot1, Wrel2, Wroot2, Wrel3, Wroot3, Wlin, brel3, blin,
      M1, M2, cvec, WbT1r, WbT1o, WbT2r, WbT2o);
  csr_kernel<<<nbuck, 256, 0, stream>>>(
      binned, cursors, csr_src, offsets, midoff, n_nodes, nbuck, halfThresh);

  fused_layer_kernel<<<fused_blocks, 256, 0, stream>>>(
      hX, offsets, midoff, csr_src, WbT1r, WbT1o, brel1, h1, n_nodes, 1);
  fused_layer_kernel<<<fused_blocks, 256, 0, stream>>>(
      h1, offsets, midoff, csr_src, WbT2r, WbT2o, brel2, h2, n_nodes, 1);

  gather_pool_kernel<<<fused_blocks, 256, 0, stream>>>(
      h2, offsets, midoff, csr_src, batch, pooledA, pooledH, n_nodes);

  final_kernel<<<N_GRAPHS, 64, 0, stream>>>(
      pooledA, pooledH, M1, M2, cvec, blin, batch, out, n_nodes);
}